// Round 5
// baseline (1624.398 us; speedup 1.0000x reference)
//
#include <hip/hip_runtime.h>

// ---------------------------------------------------------------------------
// PIXBA (Mamba vision encoder + MAE masking) forward, MI355X gfx950.
// Round 5: 128x128 MFMA GEMM for the two big per-layer GEMMs; bulk one-shot
// weight conversion (ws is ~453 MB); keep 64x64 GEMM for small shapes.
// ---------------------------------------------------------------------------

#define BATCH 8
#define NPATCH 196
#define LEN_KEEP 147
#define SEQ 148            // 1 + LEN_KEEP
#define DM 768
#define DI 1536
#define DTR 48
#define DST 16
#define MTOK (BATCH*SEQ)   // 1184
#define MT MTOK

typedef __bf16 bf16_t;
typedef bf16_t bf16x8 __attribute__((ext_vector_type(8)));
typedef float  f32x4  __attribute__((ext_vector_type(4)));
typedef unsigned short u16;
typedef u16 u16x8 __attribute__((ext_vector_type(8)));

__device__ __forceinline__ u16 f2bf(float f) {
    union { float f; unsigned u; } c; c.f = f;
    unsigned r = c.u + 0x7FFFu + ((c.u >> 16) & 1u);   // RNE to bf16
    return (u16)(r >> 16);
}
__device__ __forceinline__ float bf2f(u16 u) {
    union { unsigned u; float f; } c; c.u = ((unsigned)u) << 16; return c.f;
}
__device__ __forceinline__ float sigmoidf_(float x) { return 1.f / (1.f + __expf(-x)); }

// async global -> LDS, 16 B per lane (wave-uniform LDS base, per-lane source)
__device__ __forceinline__ void gl_lds16(const void* g, void* l) {
    __builtin_amdgcn_global_load_lds(
        (const __attribute__((address_space(1))) unsigned int*)g,
        (__attribute__((address_space(3))) unsigned int*)l, 16, 0, 0);
}

// ---------------------------------------------------------------------------
// im2col: pixel (8,3,224,224) -> Apatch_bf (1568, 768), k = c*256 + i*16 + j
// ---------------------------------------------------------------------------
__global__ __launch_bounds__(256) void k_im2col(const float* __restrict__ px,
                                                u16* __restrict__ Ap) {
    int idx = blockIdx.x * 256 + threadIdx.x;       // 4 elems each
    if (idx >= 1568 * 192) return;
    int m = idx / 192, kq = (idx % 192) * 4;
    int b = m / NPATCH, p = m % NPATCH;
    int c = kq / 256, r = kq % 256, i = r / 16, j = r % 16;
    int y = (p / 14) * 16 + i, x = (p % 14) * 16 + j;
    float4 v = *reinterpret_cast<const float4*>(&px[((size_t)(b * 3 + c) * 224 + y) * 224 + x]);
    ushort4 w4 = { f2bf(v.x), f2bf(v.y), f2bf(v.z), f2bf(v.w) };
    *reinterpret_cast<ushort4*>(&Ap[(size_t)m * 768 + kq]) = w4;
}

// ---------------------------------------------------------------------------
// mask / argsort: brute-force stable rank per batch row (196 elems)
// ---------------------------------------------------------------------------
__global__ __launch_bounds__(256) void k_mask(const float* __restrict__ noise,
                                              int* __restrict__ ids_shuf,
                                              float* __restrict__ out_mask,
                                              float* __restrict__ out_restore) {
    __shared__ float sn[NPATCH];
    __shared__ int sshuf[NPATCH];
    int b = blockIdx.x, tid = threadIdx.x;
    if (tid < NPATCH) sn[tid] = noise[b * NPATCH + tid];
    __syncthreads();
    if (tid < NPATCH) {
        float nj = sn[tid];
        int rank = 0;
        for (int i = 0; i < NPATCH; ++i) {
            float ni = sn[i];
            rank += (ni < nj) || (ni == nj && i < tid);
        }
        out_restore[b * NPATCH + tid] = (float)rank;
        out_mask[b * NPATCH + tid] = (rank >= LEN_KEEP) ? 1.f : 0.f;
        sshuf[rank] = tid;
    }
    __syncthreads();
    if (tid < NPATCH) ids_shuf[b * NPATCH + tid] = sshuf[tid];
}

// ---------------------------------------------------------------------------
// build h: h[b,0]=cls+pos[0]; h[b,1+l]=embed[b, ids_shuf[b][l]]
// ---------------------------------------------------------------------------
__global__ __launch_bounds__(256) void k_build_h(const float* __restrict__ embed,
                                                 const int* __restrict__ ids_shuf,
                                                 const float* __restrict__ cls,
                                                 const float* __restrict__ pos,
                                                 float* __restrict__ h) {
    int blk = blockIdx.x;                // 0..1183
    int b = blk / SEQ, t = blk % SEQ, tid = threadIdx.x;
    size_t ob = (size_t)blk * DM;
    if (t == 0) {
        for (int i = tid; i < DM; i += 256) h[ob + i] = cls[i] + pos[i];
    } else {
        int j = ids_shuf[b * NPATCH + (t - 1)];
        const float* src = embed + (size_t)(b * NPATCH + j) * DM;
        for (int i = tid; i < DM; i += 256) h[ob + i] = src[i];
    }
}

// ---------------------------------------------------------------------------
// LayerNorm (eps 1e-12), 768 wide, one row per block. OUT_BF: bf16 or f32 out.
// ---------------------------------------------------------------------------
template <int OUT_BF>
__global__ __launch_bounds__(256) void k_layernorm(const float* __restrict__ in,
                                                   const float* __restrict__ w,
                                                   const float* __restrict__ b,
                                                   void* __restrict__ outv) {
    int row = blockIdx.x, tid = threadIdx.x;
    const float* x = in + (size_t)row * DM;
    float v0 = x[tid], v1 = x[tid + 256], v2 = x[tid + 512];
    float s = v0 + v1 + v2, q = v0 * v0 + v1 * v1 + v2 * v2;
#pragma unroll
    for (int off = 32; off; off >>= 1) {
        s += __shfl_down(s, off, 64);
        q += __shfl_down(q, off, 64);
    }
    __shared__ float ss[4], sq[4];
    int wid = tid >> 6, lane = tid & 63;
    if (lane == 0) { ss[wid] = s; sq[wid] = q; }
    __syncthreads();
    float st = ss[0] + ss[1] + ss[2] + ss[3];
    float qt = sq[0] + sq[1] + sq[2] + sq[3];
    float mu = st * (1.f / DM);
    float var = qt * (1.f / DM) - mu * mu;
    float rstd = rsqrtf(var + 1e-12f);
    float r0 = (v0 - mu) * rstd * w[tid]       + b[tid];
    float r1 = (v1 - mu) * rstd * w[tid + 256] + b[tid + 256];
    float r2 = (v2 - mu) * rstd * w[tid + 512] + b[tid + 512];
    if (OUT_BF) {
        u16* o = (u16*)outv + (size_t)row * DM;
        o[tid] = f2bf(r0); o[tid + 256] = f2bf(r1); o[tid + 512] = f2bf(r2);
    } else {
        float* o = (float*)outv + (size_t)row * DM;
        o[tid] = r0; o[tid + 256] = r1; o[tid + 512] = r2;
    }
}

// ---------------------------------------------------------------------------
// Pipelined bf16 NT-GEMM, BM=BN=64, BK=64, 4 waves (2x2), 2-phase dbuf.
// (used for small/odd shapes)
// EPI: 1=f32 atomicAdd, 2=embed f32 (+e0[n]+e1[(1+m%196)*768+n]),
//      3=softplus(v+e0[n])->bf16, 4=bf16 store, 5=softplus(v+e0[m])->bf16
// ---------------------------------------------------------------------------
template <int EPI>
__global__ __launch_bounds__(256) void gemm64(
    const u16* __restrict__ A, int lda, int M,
    const u16* __restrict__ B, int ldb, int N,
    void* __restrict__ Cv, int ldc, int kChunk,
    const float* __restrict__ e0, const float* __restrict__ e1) {
    __shared__ u16 sm[2][128 * 64];
    const int tid = threadIdx.x;
    const int m0 = blockIdx.x * 64, n0 = blockIdx.y * 64;
    const int kStart = blockIdx.z * kChunk;
    const int lane = tid & 63, wid = tid >> 6;
    const int wr = wid >> 1, wc = wid & 1;
    const int lr = lane & 15, lg = lane >> 4;
    const int subrow = lane >> 3, kpart = lane & 7;
    const int kel = 8 * (kpart ^ subrow);       // pre-swizzled source k-offset

    f32x4 acc[2][2] = {};
    const int nt = kChunk / 64;

    {
        const int k0 = kStart;
#pragma unroll
        for (int s = 0; s < 2; ++s) {
            int rb = wid * 16 + s * 8;
            int ra = min(m0 + rb + subrow, M - 1);
            gl_lds16(A + (size_t)ra * lda + k0 + kel, &sm[0][rb * 64]);
            int rn = min(n0 + rb + subrow, N - 1);
            gl_lds16(B + (size_t)rn * ldb + k0 + kel, &sm[0][64 * 64 + rb * 64]);
        }
    }
    __syncthreads();
    for (int t = 0; t < nt; ++t) {
        if (t + 1 < nt) {
            const int k0 = kStart + (t + 1) * 64;
            const int buf = (t + 1) & 1;
#pragma unroll
            for (int s = 0; s < 2; ++s) {
                int rb = wid * 16 + s * 8;
                int ra = min(m0 + rb + subrow, M - 1);
                gl_lds16(A + (size_t)ra * lda + k0 + kel, &sm[buf][rb * 64]);
                int rn = min(n0 + rb + subrow, N - 1);
                gl_lds16(B + (size_t)rn * ldb + k0 + kel, &sm[buf][64 * 64 + rb * 64]);
            }
        }
        {
            const u16* sA = &sm[t & 1][0];
            const u16* sB = &sm[t & 1][64 * 64];
#pragma unroll
            for (int kk = 0; kk < 2; ++kk) {
                bf16x8 av[2], bv[2];
#pragma unroll
                for (int i = 0; i < 2; ++i) {
                    int row = wr * 32 + i * 16 + lr;
                    int e = (kk * 32 + lg * 8) ^ ((row & 7) << 3);
                    av[i] = *reinterpret_cast<const bf16x8*>(sA + row * 64 + e);
                }
#pragma unroll
                for (int j = 0; j < 2; ++j) {
                    int row = wc * 32 + j * 16 + lr;
                    int e = (kk * 32 + lg * 8) ^ ((row & 7) << 3);
                    bv[j] = *reinterpret_cast<const bf16x8*>(sB + row * 64 + e);
                }
#pragma unroll
                for (int i = 0; i < 2; ++i)
#pragma unroll
                    for (int j = 0; j < 2; ++j)
                        acc[i][j] = __builtin_amdgcn_mfma_f32_16x16x32_bf16(
                            av[i], bv[j], acc[i][j], 0, 0, 0);
            }
        }
        __syncthreads();
    }
#pragma unroll
    for (int i = 0; i < 2; ++i)
#pragma unroll
        for (int r = 0; r < 4; ++r) {
            int m = m0 + wr * 32 + i * 16 + lg * 4 + r;
            if (m >= M) continue;
#pragma unroll
            for (int j = 0; j < 2; ++j) {
                int n = n0 + wc * 32 + j * 16 + lr;
                if (n >= N) continue;
                float v = acc[i][j][r];
                size_t idx = (size_t)m * ldc + n;
                if (EPI == 1) {
                    atomicAdd((float*)Cv + idx, v);
                } else if (EPI == 2) {
                    ((float*)Cv)[idx] = v + e0[n] + e1[(size_t)(1 + (m % NPATCH)) * DM + n];
                } else if (EPI == 3) {
                    float x = v + e0[n];
                    ((u16*)Cv)[idx] = f2bf(x > 20.f ? x : log1pf(__expf(x)));
                } else if (EPI == 4) {
                    ((u16*)Cv)[idx] = f2bf(v);
                } else {  // 5: softplus with row (m) bias -> bf16
                    float x = v + e0[m];
                    ((u16*)Cv)[idx] = f2bf(x > 20.f ? x : log1pf(__expf(x)));
                }
            }
        }
}

// ---------------------------------------------------------------------------
// Pipelined bf16 NT-GEMM, BM=BN=128, BK=64, 4 waves (2x2), each 64x64 out.
// 2-phase dbuf, gl_lds16 + XOR swizzle. LDS 64 KB -> 2 blocks/CU.
// EPI: 1=f32 atomicAdd, 4=bf16 store
// ---------------------------------------------------------------------------
template <int EPI>
__global__ __launch_bounds__(256) void gemm128(
    const u16* __restrict__ A, int lda, int M,
    const u16* __restrict__ B, int ldb, int N,
    void* __restrict__ Cv, int ldc, int kChunk) {
    __shared__ u16 sm[2][2 * 128 * 64];
    const int tid = threadIdx.x;
    const int m0 = blockIdx.x * 128, n0 = blockIdx.y * 128;
    const int kStart = blockIdx.z * kChunk;
    const int lane = tid & 63, wid = tid >> 6;
    const int wr = wid >> 1, wc = wid & 1;
    const int lr = lane & 15, lg = lane >> 4;
    const int subrow = lane >> 3, kpart = lane & 7;
    const int kel = 8 * (kpart ^ subrow);

    f32x4 acc[4][4] = {};
    const int nt = kChunk / 64;

#define STAGE128(buf, k0)                                                     \
    {                                                                         \
        _Pragma("unroll")                                                     \
        for (int s = 0; s < 4; ++s) {                                         \
            int rb = wid * 32 + s * 8;                                        \
            int ra = min(m0 + rb + subrow, M - 1);                            \
            gl_lds16(A + (size_t)ra * lda + (k0) + kel, &sm[buf][rb * 64]);   \
            int rn = min(n0 + rb + subrow, N - 1);                            \
            gl_lds16(B + (size_t)rn * ldb + (k0) + kel,                       \
                     &sm[buf][128 * 64 + rb * 64]);                           \
        }                                                                     \
    }

    STAGE128(0, kStart);
    __syncthreads();
    for (int t = 0; t < nt; ++t) {
        if (t + 1 < nt) STAGE128((t + 1) & 1, kStart + (t + 1) * 64);
        const u16* sA = &sm[t & 1][0];
        const u16* sB = &sm[t & 1][128 * 64];
#pragma unroll
        for (int kk = 0; kk < 2; ++kk) {
            bf16x8 av[4], bv[4];
#pragma unroll
            for (int i = 0; i < 4; ++i) {
                int row = wr * 64 + i * 16 + lr;
                int e = (kk * 32 + lg * 8) ^ ((row & 7) << 3);
                av[i] = *reinterpret_cast<const bf16x8*>(sA + row * 64 + e);
            }
#pragma unroll
            for (int j = 0; j < 4; ++j) {
                int row = wc * 64 + j * 16 + lr;
                int e = (kk * 32 + lg * 8) ^ ((row & 7) << 3);
                bv[j] = *reinterpret_cast<const bf16x8*>(sB + row * 64 + e);
            }
#pragma unroll
            for (int i = 0; i < 4; ++i)
#pragma unroll
                for (int j = 0; j < 4; ++j)
                    acc[i][j] = __builtin_amdgcn_mfma_f32_16x16x32_bf16(
                        av[i], bv[j], acc[i][j], 0, 0, 0);
        }
        __syncthreads();
    }
#undef STAGE128
#pragma unroll
    for (int i = 0; i < 4; ++i)
#pragma unroll
        for (int r = 0; r < 4; ++r) {
            int m = m0 + wr * 64 + i * 16 + lg * 4 + r;
            if (m >= M) continue;
#pragma unroll
            for (int j = 0; j < 4; ++j) {
                int n = n0 + wc * 64 + j * 16 + lr;
                if (n >= N) continue;
                float v = acc[i][j][r];
                size_t idx = (size_t)m * ldc + n;
                if (EPI == 1) atomicAdd((float*)Cv + idx, v);
                else          ((u16*)Cv)[idx] = f2bf(v);
            }
        }
}

// ---------------------------------------------------------------------------
// Causal depthwise conv(4)+silu on channel-major xs^T.
// ---------------------------------------------------------------------------
template <int TC>
__device__ __forceinline__ void conv_piece(const u16* __restrict__ xrow,
                                           const float w0, const float w1,
                                           const float w2, const float w3,
                                           const float cbv,
                                           u16* __restrict__ sout) {
    constexpr int START = (TC == 0) ? 0 : (TC == 1) ? 32 : (TC == 2) ? 64 : 104;
    u16x8 buf[6];
#pragma unroll
    for (int i = 0; i < 6; ++i)
        buf[i] = *reinterpret_cast<const u16x8*>(xrow + START + 8 * i);
    const float wj[4] = { w0, w1, w2, w3 };
#pragma unroll
    for (int i = 0; i < 37; ++i) {
        const int t = TC * 37 + i;
        float acc = cbv;
#pragma unroll
        for (int j = 0; j < 4; ++j) {
            const int q = t - 3 + j;
            if (TC == 0 && q < 0) continue;      // folds at compile time
            const int idx = q - START;
            acc += bf2f(buf[idx >> 3][idx & 7]) * wj[j];
        }
        acc = acc * sigmoidf_(acc);
        sout[t] = f2bf(acc);
    }
}

__global__ __launch_bounds__(256) void k_conv(
    const u16* __restrict__ xzT,    // [3072][1184] (xs = rows 0..1535)
    const float* __restrict__ cw,   // [1536][4]
    const float* __restrict__ cb,   // [1536]
    u16* __restrict__ xcT,          // [1536][1184]
    u16* __restrict__ xcTok,        // [1184][1536]
    float* __restrict__ xdbl) {     // [1184][80] -> zeroed
    __shared__ u16 sxc[64][152];
    const int tid = threadIdx.x;
    const int d0 = blockIdx.x * 64, b = blockIdx.y;
    const int dl = tid & 63, tc = tid >> 6;
    const int d = d0 + dl;
    float4 w4 = *reinterpret_cast<const float4*>(&cw[d * 4]);
    float cbv = cb[d];
    const u16* xrow = xzT + (size_t)d * MT + b * SEQ;
    switch (tc) {
        case 0: conv_piece<0>(xrow, w4.x, w4.y, w4.z, w4.w, cbv, &sxc[dl][0]); break;
        case 1: conv_piece<1>(xrow, w4.x, w4.y, w4.z, w4.w, cbv, &sxc[dl][0]); break;
        case 2: conv_piece<2>(xrow, w4.x, w4.y, w4.z, w4.w, cbv, &sxc[dl][0]); break;
        default: conv_piece<3>(xrow, w4.x, w4.y, w4.z, w4.w, cbv, &sxc[dl][0]); break;
    }
    if (blockIdx.x == 0) {          // zero xdbl slice for this batch
        float4* xo = reinterpret_cast<float4*>(xdbl + (size_t)b * SEQ * 80);
        for (int c = tid; c < SEQ * 20; c += 256) xo[c] = make_float4(0.f, 0.f, 0.f, 0.f);
    }
    __syncthreads();
    for (int c = tid; c < 64 * 19; c += 256) {
        int dd = c / 19, ch = c % 19;
        size_t gbase = (size_t)(d0 + dd) * MT + b * SEQ;
        if (ch < 18)
            *reinterpret_cast<u16x8*>(&xcT[gbase + ch * 8]) =
                *reinterpret_cast<const u16x8*>(&sxc[dd][ch * 8]);
        else
            *reinterpret_cast<ushort4*>(&xcT[gbase + 144]) =
                *reinterpret_cast<const ushort4*>(&sxc[dd][144]);
    }
    if (tid < SEQ) {
        int t = tid;
        size_t gb = (size_t)(b * SEQ + t) * DI + d0;
#pragma unroll
        for (int g = 0; g < 8; ++g) {
            u16x8 v;
#pragma unroll
            for (int e = 0; e < 8; ++e) v[e] = sxc[g * 8 + e][t];
            *reinterpret_cast<u16x8*>(&xcTok[gb + g * 8]) = v;
        }
    }
}

// ---------------------------------------------------------------------------
// Selective scan: 16 lanes per (b,d); 8-step chunks, vectorized loads.
// ---------------------------------------------------------------------------
__global__ __launch_bounds__(256) void k_scan(
    const u16* __restrict__ dtT,    // [1536][1184] bf16
    const u16* __restrict__ xcT,    // [1536][1184] bf16
    const u16* __restrict__ xzT,    // [3072][1184] bf16 (z = rows 1536..)
    const float* __restrict__ xdT,  // [32][1184] f32: rows 0..15 = B, 16..31 = C
    const float* __restrict__ A_log,// [1536][16] (layer slice)
    const float* __restrict__ Dp,   // [1536]
    u16* __restrict__ y) {          // [1184][1536] bf16 token-major
    __shared__ u16 sy[16][152];
    const int tid = threadIdx.x;
    const int d0 = blockIdx.x * 16, b = blockIdx.y;
    const int dl = tid >> 4, n = tid & 15;
    const int d = d0 + dl;
    const float An = -__expf(A_log[d * DST + n]);
    const float Dv = Dp[d];
    const u16* dtrow = dtT + (size_t)d * MT + b * SEQ;
    const u16* xcrow = xcT + (size_t)d * MT + b * SEQ;
    const u16* zrow  = xzT + (size_t)(DI + d) * MT + b * SEQ;
    const float* Brow = xdT + (size_t)n * MT + b * SEQ;
    const float* Crow = xdT + (size_t)(16 + n) * MT + b * SEQ;
    float h = 0.f;
    for (int t0 = 0; t0 < SEQ; t0 += 8) {
        u16x8 dt8 = *reinterpret_cast<const u16x8*>(dtrow + t0);
        u16x8 xc8 = *reinterpret_cast<const u16x8*>(xcrow + t0);
        u16x8 z8  = *reinterpret_cast<const u16x8*>(zrow + t0);
        float4 B0 = *reinterpret_cast<const float4*>(Brow + t0);
        float4 B1 = *reinterpret_cast<const float4*>(Brow + t0 + 4);
        float4 C0 = *reinterpret_cast<const float4*>(Crow + t0);
        float4 C1 = *reinterpret_cast<const float4*>(Crow + t0 + 4);
        const float Ba[8] = { B0.x, B0.y, B0.z, B0.w, B1.x, B1.y, B1.z, B1.w };
        const float Ca[8] = { C0.x, C0.y, C0.z, C0.w, C1.x, C1.y, C1.z, C1.w };
#pragma unroll
        for (int j = 0; j < 8; ++j) {
            if (t0 + j < SEQ) {
                float dtv = bf2f(dt8[j]);
                float xcv = bf2f(xc8[j]);
                float e = __expf(dtv * An);
                h = e * h + (dtv * xcv) * Ba[j];
                float yp = h * Ca[j];
                yp += __shfl_xor(yp, 1, 64);
                yp += __shfl_xor(yp, 2, 64);
                yp += __shfl_xor(yp, 4, 64);
                yp += __shfl_xor(yp, 8, 64);
                if (n == 0) {
                    float zv = bf2f(z8[j]);
                    sy[dl][t0 + j] = f2bf((yp + xcv * Dv) * (zv * sigmoidf_(zv)));
                }
            }
        }
    }
    __syncthreads();
    if (tid < SEQ) {
        int t = tid;
        size_t gb = (size_t)(b * SEQ + t) * DI + d0;
#pragma unroll
        for (int g = 0; g < 2; ++g) {
            u16x8 v;
#pragma unroll
            for (int e = 0; e < 8; ++e) v[e] = sy[g * 8 + e][t];
            *reinterpret_cast<u16x8*>(&y[gb + g * 8]) = v;
        }
    }
}

// ---------------------------------------------------------------------------
// converts
// ---------------------------------------------------------------------------
__global__ __launch_bounds__(256) void k_cvt(const float* __restrict__ s,
                                             u16* __restrict__ d, int n4) {
    int i = blockIdx.x * 256 + threadIdx.x;
    if (i >= n4) return;
    float4 v = *reinterpret_cast<const float4*>(s + (size_t)i * 4);
    ushort4 w4 = { f2bf(v.x), f2bf(v.y), f2bf(v.z), f2bf(v.w) };
    *reinterpret_cast<ushort4*>(d + (size_t)i * 4) = w4;
}

// Bulk all-layer weight convert. Quad regions:
//   W_in 12x3072x768, W_out 12x768x1536, W_x 12x80x1536,
//   W_dt 12x1536x48 -> padded 12x1536x64.
#define QWI 7077888L
#define QWO 3538944L
#define QWX 368640L
#define QWD 294912L
__global__ __launch_bounds__(256) void k_cvtw_all(
    const float* __restrict__ Wi, const float* __restrict__ Wo,
    const float* __restrict__ Wx, const float* __restrict__ Wd,
    u16* __restrict__ oi, u16* __restrict__ oo,
    u16* __restrict__ ox, u16* __restrict__ od) {
    long q = (long)blockIdx.x * 256 + threadIdx.x;
    if (q < QWI) {
        long e = q * 4;
        float4 v = *reinterpret_cast<const float4*>(Wi + e);
        ushort4 w4 = { f2bf(v.x), f2bf(v.y), f2bf(v.z), f2bf(v.w) };
        *reinterpret_cast<ushort4*>(oi + e) = w4;
    } else if (q < QWI + QWO) {
        long e = (q - QWI) * 4;
        float4 v = *reinterpret_cast<const float4*>(Wo + e);
        ushort4 w4 = { f2bf(v.x), f2bf(v.y), f2bf(v.z), f2bf(v.w) };
        *reinterpret_cast<ushort4*>(oo + e) = w4;
    } else if (q < QWI + QWO + QWX) {
        long e = (q - QWI - QWO) * 4;
        float4 v = *reinterpret_cast<const float4*>(Wx + e);
        ushort4 w4 = { f2bf(v.x), f2bf(v.y), f2bf(v.z), f2bf(v.w) };
        *reinterpret_cast<ushort4*>(ox + e) = w4;
    } else {
        long e = (q - QWI - QWO - QWX) * 4;      // dest elem in [0, 12*1536*64)
        int l = (int)(e / 98304);
        int rem = (int)(e % 98304);
        int rw = rem >> 6, c = rem & 63;
        ushort4 w4 = { 0, 0, 0, 0 };
        if (c < DTR) {
            float4 v = *reinterpret_cast<const float4*>(
                Wd + (size_t)l * (DI * DTR) + (size_t)rw * DTR + c);
            w4 = { f2bf(v.x), f2bf(v.y), f2bf(v.z), f2bf(v.w) };
        }
        *reinterpret_cast<ushort4*>(od + e) = w4;
    }
}

// xdbl [1184][80] f32 -> xdbl_bf [1184][64] bf16 (cols 0..47, zero-pad)
//                     -> xdT [32][1184] f32 (cols 48..79 transposed)
__global__ __launch_bounds__(256) void k_cvt_xdbl(const float* __restrict__ x,
                                                  u16* __restrict__ obf,
                                                  float* __restrict__ oT) {
    int i = blockIdx.x * 256 + threadIdx.x;
    if (i < MTOK * 64) {
        int r = i >> 6, c = i & 63;
        obf[i] = (c < DTR) ? f2bf(x[(size_t)r * 80 + c]) : (u16)0;
    } else {
        int j = i - MTOK * 64;
        if (j < 32 * MTOK) {
            int rr = j / MTOK, m = j - rr * MTOK;
            oT[(size_t)rr * MTOK + m] = x[(size_t)m * 80 + 48 + rr];
        }
    }
}

// ---------------------------------------------------------------------------
extern "C" void kernel_launch(void* const* d_in, const int* in_sizes, int n_in,
                              void* d_out, int out_size, void* d_ws, size_t ws_size,
                              hipStream_t stream) {
    const float* pixel  = (const float*)d_in[0];
    const float* noise  = (const float*)d_in[1];
    const float* conv_w = (const float*)d_in[2];
    const float* conv_b = (const float*)d_in[3];
    const float* cls    = (const float*)d_in[4];
    const float* pos    = (const float*)d_in[5];
    const float* ln_w   = (const float*)d_in[6];
    const float* ln_b   = (const float*)d_in[7];
    const float* W_in   = (const float*)d_in[8];
    const float* c1w    = (const float*)d_in[9];
    const float* c1b    = (const float*)d_in[10];
    const float* W_x    = (const float*)d_in[11];
    const float* W_dt   = (const float*)d_in[12];
    const float* dtb    = (const float*)d_in[13];
    const float* A_log  = (const float*)d_in[14];
    const float* Dp     = (const float*)d_in[15];
    const float* W_out  = (const float*)d_in[16];
    const float* lnf_w  = (const float*)d_in[17];
    const float* lnf_b  = (const float*)d_in[18];

    float* out = (float*)d_out;
    float* h = out;                                   // [1184][768] f32
    float* out_mask    = out + MTOK * DM;
    float* out_restore = out + MTOK * DM + BATCH * NPATCH;

    // ---- workspace layout (byte offsets, 64-aligned) ----
    char* wsb = (char*)d_ws;
    u16*  xzT     = (u16*)(wsb + 0);          // 7,274,496 (+64)
    u16*  xcT     = (u16*)(wsb + 7274560);    // 3,637,248 (+64)
    u16*  xcTok   = (u16*)(wsb + 10911872);   // 3,637,248
    u16*  dtT     = (u16*)(wsb + 14549120);   // 3,637,248 (+64)
    u16*  yb      = (u16*)(wsb + 18186432);   // 3,637,248
    u16*  xln_bf  = (u16*)(wsb + 21823680);   // 1,818,624
    float* xdbl   = (float*)(wsb + 23642304); // 378,880
    u16*  xdbl_bf = (u16*)(wsb + 24021184);   // 151,552
    float* xdT    = (float*)(wsb + 24172736); // 151,552 (+64)
    u16*  apatch  = (u16*)(wsb + 24324352);   // 2,408,448
    float* embed  = (float*)(wsb + 26732800); // 4,816,896
    int*  ids     = (int*)(wsb + 31549696);   // 6,272 (+64)
    u16*  cw_bf   = (u16*)(wsb + 31556032);   // 1,179,648
    u16*  wi_all  = (u16*)(wsb + 32735680);   // 56,623,104
    u16*  wo_all  = wi_all + QWI * 4;         // 28,311,552
    u16*  wx_all  = wo_all + QWO * 4;         // 2,949,120
    u16*  wd_all  = wx_all + QWX * 4;         // 2,359,296 -> end ~123 MB

    // ---- setup ----
    k_im2col<<<1176, 256, 0, stream>>>(pixel, apatch);
    k_mask<<<BATCH, 256, 0, stream>>>(noise, ids, out_mask, out_restore);
    k_cvt<<<576, 256, 0, stream>>>(conv_w, cw_bf, 147456);
    k_cvtw_all<<<44064, 256, 0, stream>>>(W_in, W_out, W_x, W_dt,
                                          wi_all, wo_all, wx_all, wd_all);
    gemm64<2><<<dim3(25, 12, 1), 256, 0, stream>>>(
        apatch, 768, 1568, cw_bf, 768, 768, embed, DM, 768, conv_b, pos);
    k_build_h<<<MTOK, 256, 0, stream>>>(embed, ids, cls, pos, h);

    // ---- layers ----
    for (int l = 0; l < 12; ++l) {
        const u16* wi = wi_all + (size_t)l * 2359296;
        const u16* wo = wo_all + (size_t)l * 1179648;
        const u16* wx = wx_all + (size_t)l * 122880;
        const u16* wd = wd_all + (size_t)l * 98304;
        k_layernorm<1><<<MTOK, 256, 0, stream>>>(h, ln_w + l * DM, ln_b + l * DM, xln_bf);
        // xz^T = W_in @ xln^T : A=W_in rows (3072), B=xln rows (1184)
        gemm128<4><<<dim3(24, 10, 1), 256, 0, stream>>>(
            wi, DM, 3072, xln_bf, DM, MTOK, xzT, MT, DM);
        // conv+silu -> xc^T and token-major xc; zero xdbl
        k_conv<<<dim3(24, 8), 256, 0, stream>>>(
            xzT, c1w + l * DI * 4, c1b + l * DI, xcT, xcTok, xdbl);
        // xdbl += xc @ W_x^T (split-K 8 x 192)
        gemm64<1><<<dim3(19, 2, 8), 256, 0, stream>>>(
            xcTok, DI, MTOK, wx, DI, 80, xdbl, 80, 192, nullptr, nullptr);
        k_cvt_xdbl<<<444, 256, 0, stream>>>(xdbl, xdbl_bf, xdT);
        // dt^T = softplus(W_dt @ xdbl^T + dtb[m])
        gemm64<5><<<dim3(24, 19, 1), 256, 0, stream>>>(
            wd, 64, DI, xdbl_bf, 64, MTOK, dtT, MT, 64, dtb + l * DI, nullptr);
        k_scan<<<dim3(96, 8), 256, 0, stream>>>(
            dtT, xcT, xzT, xdT, A_log + (size_t)l * DI * DST, Dp + l * DI, yb);
        // h += y @ W_out^T (split-K 4 x 384, atomicAdd into residual)
        gemm128<1><<<dim3(10, 6, 4), 256, 0, stream>>>(
            yb, DI, MTOK, wo, DI, DM, h, DM, 384);
    }
    k_layernorm<0><<<MTOK, 256, 0, stream>>>(h, lnf_w, lnf_b, h);
}

// Round 7
// 1494.510 us; speedup vs baseline: 1.0869x; 1.0869x over previous
//
#include <hip/hip_runtime.h>

// ---------------------------------------------------------------------------
// PIXBA (Mamba vision encoder + MAE masking) forward, MI355X gfx950.
// Round 6 (resubmit after infra timeout): revert big GEMMs to 64x64
// (occupancy > per-block density at these sizes); fast region-based bulk
// weight cvt; dt-GEMM reads f32 xdbl directly; scan stages B/C from f32 xdbl.
// ---------------------------------------------------------------------------

#define BATCH 8
#define NPATCH 196
#define LEN_KEEP 147
#define SEQ 148            // 1 + LEN_KEEP
#define DM 768
#define DI 1536
#define DTR 48
#define DST 16
#define MTOK (BATCH*SEQ)   // 1184
#define MT MTOK

typedef __bf16 bf16_t;
typedef bf16_t bf16x8 __attribute__((ext_vector_type(8)));
typedef float  f32x4  __attribute__((ext_vector_type(4)));
typedef unsigned short u16;
typedef u16 u16x8 __attribute__((ext_vector_type(8)));

__device__ __forceinline__ u16 f2bf(float f) {
    union { float f; unsigned u; } c; c.f = f;
    unsigned r = c.u + 0x7FFFu + ((c.u >> 16) & 1u);   // RNE to bf16
    return (u16)(r >> 16);
}
__device__ __forceinline__ float bf2f(u16 u) {
    union { unsigned u; float f; } c; c.u = ((unsigned)u) << 16; return c.f;
}
__device__ __forceinline__ float sigmoidf_(float x) { return 1.f / (1.f + __expf(-x)); }

// async global -> LDS, 16 B per lane (wave-uniform LDS base, per-lane source)
__device__ __forceinline__ void gl_lds16(const void* g, void* l) {
    __builtin_amdgcn_global_load_lds(
        (const __attribute__((address_space(1))) unsigned int*)g,
        (__attribute__((address_space(3))) unsigned int*)l, 16, 0, 0);
}

// ---------------------------------------------------------------------------
// im2col: pixel (8,3,224,224) -> Apatch_bf (1568, 768), k = c*256 + i*16 + j
// ---------------------------------------------------------------------------
__global__ __launch_bounds__(256) void k_im2col(const float* __restrict__ px,
                                                u16* __restrict__ Ap) {
    int idx = blockIdx.x * 256 + threadIdx.x;       // 4 elems each
    if (idx >= 1568 * 192) return;
    int m = idx / 192, kq = (idx % 192) * 4;
    int b = m / NPATCH, p = m % NPATCH;
    int c = kq / 256, r = kq % 256, i = r / 16, j = r % 16;
    int y = (p / 14) * 16 + i, x = (p % 14) * 16 + j;
    float4 v = *reinterpret_cast<const float4*>(&px[((size_t)(b * 3 + c) * 224 + y) * 224 + x]);
    ushort4 w4 = { f2bf(v.x), f2bf(v.y), f2bf(v.z), f2bf(v.w) };
    *reinterpret_cast<ushort4*>(&Ap[(size_t)m * 768 + kq]) = w4;
}

// ---------------------------------------------------------------------------
// mask / argsort: brute-force stable rank per batch row (196 elems)
// ---------------------------------------------------------------------------
__global__ __launch_bounds__(256) void k_mask(const float* __restrict__ noise,
                                              int* __restrict__ ids_shuf,
                                              float* __restrict__ out_mask,
                                              float* __restrict__ out_restore) {
    __shared__ float sn[NPATCH];
    __shared__ int sshuf[NPATCH];
    int b = blockIdx.x, tid = threadIdx.x;
    if (tid < NPATCH) sn[tid] = noise[b * NPATCH + tid];
    __syncthreads();
    if (tid < NPATCH) {
        float nj = sn[tid];
        int rank = 0;
        for (int i = 0; i < NPATCH; ++i) {
            float ni = sn[i];
            rank += (ni < nj) || (ni == nj && i < tid);
        }
        out_restore[b * NPATCH + tid] = (float)rank;
        out_mask[b * NPATCH + tid] = (rank >= LEN_KEEP) ? 1.f : 0.f;
        sshuf[rank] = tid;
    }
    __syncthreads();
    if (tid < NPATCH) ids_shuf[b * NPATCH + tid] = sshuf[tid];
}

// ---------------------------------------------------------------------------
// build h: h[b,0]=cls+pos[0]; h[b,1+l]=embed[b, ids_shuf[b][l]]
// ---------------------------------------------------------------------------
__global__ __launch_bounds__(256) void k_build_h(const float* __restrict__ embed,
                                                 const int* __restrict__ ids_shuf,
                                                 const float* __restrict__ cls,
                                                 const float* __restrict__ pos,
                                                 float* __restrict__ h) {
    int blk = blockIdx.x;                // 0..1183
    int b = blk / SEQ, t = blk % SEQ, tid = threadIdx.x;
    size_t ob = (size_t)blk * DM;
    if (t == 0) {
        for (int i = tid; i < DM; i += 256) h[ob + i] = cls[i] + pos[i];
    } else {
        int j = ids_shuf[b * NPATCH + (t - 1)];
        const float* src = embed + (size_t)(b * NPATCH + j) * DM;
        for (int i = tid; i < DM; i += 256) h[ob + i] = src[i];
    }
}

// ---------------------------------------------------------------------------
// LayerNorm (eps 1e-12), 768 wide, one row per block. OUT_BF: bf16 or f32 out.
// ---------------------------------------------------------------------------
template <int OUT_BF>
__global__ __launch_bounds__(256) void k_layernorm(const float* __restrict__ in,
                                                   const float* __restrict__ w,
                                                   const float* __restrict__ b,
                                                   void* __restrict__ outv) {
    int row = blockIdx.x, tid = threadIdx.x;
    const float* x = in + (size_t)row * DM;
    float v0 = x[tid], v1 = x[tid + 256], v2 = x[tid + 512];
    float s = v0 + v1 + v2, q = v0 * v0 + v1 * v1 + v2 * v2;
#pragma unroll
    for (int off = 32; off; off >>= 1) {
        s += __shfl_down(s, off, 64);
        q += __shfl_down(q, off, 64);
    }
    __shared__ float ss[4], sq[4];
    int wid = tid >> 6, lane = tid & 63;
    if (lane == 0) { ss[wid] = s; sq[wid] = q; }
    __syncthreads();
    float st = ss[0] + ss[1] + ss[2] + ss[3];
    float qt = sq[0] + sq[1] + sq[2] + sq[3];
    float mu = st * (1.f / DM);
    float var = qt * (1.f / DM) - mu * mu;
    float rstd = rsqrtf(var + 1e-12f);
    float r0 = (v0 - mu) * rstd * w[tid]       + b[tid];
    float r1 = (v1 - mu) * rstd * w[tid + 256] + b[tid + 256];
    float r2 = (v2 - mu) * rstd * w[tid + 512] + b[tid + 512];
    if (OUT_BF) {
        u16* o = (u16*)outv + (size_t)row * DM;
        o[tid] = f2bf(r0); o[tid + 256] = f2bf(r1); o[tid + 512] = f2bf(r2);
    } else {
        float* o = (float*)outv + (size_t)row * DM;
        o[tid] = r0; o[tid + 256] = r1; o[tid + 512] = r2;
    }
}

// ---------------------------------------------------------------------------
// Pipelined bf16 NT-GEMM, BM=BN=64, BK=64, 4 waves (2x2), 2-phase dbuf.
// gl_lds16 + XOR swizzle (LDS[row][g] = global[row][g^(row&7)], 8-elem groups).
// EPI: 1=f32 atomicAdd, 2=embed f32 (+e0[n]+e1[(1+m%196)*768+n]), 4=bf16 store
// ---------------------------------------------------------------------------
template <int EPI>
__global__ __launch_bounds__(256) void gemm64(
    const u16* __restrict__ A, int lda, int M,
    const u16* __restrict__ B, int ldb, int N,
    void* __restrict__ Cv, int ldc, int kChunk,
    const float* __restrict__ e0, const float* __restrict__ e1) {
    __shared__ u16 sm[2][128 * 64];
    const int tid = threadIdx.x;
    const int m0 = blockIdx.x * 64, n0 = blockIdx.y * 64;
    const int kStart = blockIdx.z * kChunk;
    const int lane = tid & 63, wid = tid >> 6;
    const int wr = wid >> 1, wc = wid & 1;
    const int lr = lane & 15, lg = lane >> 4;
    const int subrow = lane >> 3, kpart = lane & 7;
    const int kel = 8 * (kpart ^ subrow);       // pre-swizzled source k-offset

    f32x4 acc[2][2] = {};
    const int nt = kChunk / 64;

    {
        const int k0 = kStart;
#pragma unroll
        for (int s = 0; s < 2; ++s) {
            int rb = wid * 16 + s * 8;
            int ra = min(m0 + rb + subrow, M - 1);
            gl_lds16(A + (size_t)ra * lda + k0 + kel, &sm[0][rb * 64]);
            int rn = min(n0 + rb + subrow, N - 1);
            gl_lds16(B + (size_t)rn * ldb + k0 + kel, &sm[0][64 * 64 + rb * 64]);
        }
    }
    __syncthreads();
    for (int t = 0; t < nt; ++t) {
        if (t + 1 < nt) {
            const int k0 = kStart + (t + 1) * 64;
            const int buf = (t + 1) & 1;
#pragma unroll
            for (int s = 0; s < 2; ++s) {
                int rb = wid * 16 + s * 8;
                int ra = min(m0 + rb + subrow, M - 1);
                gl_lds16(A + (size_t)ra * lda + k0 + kel, &sm[buf][rb * 64]);
                int rn = min(n0 + rb + subrow, N - 1);
                gl_lds16(B + (size_t)rn * ldb + k0 + kel, &sm[buf][64 * 64 + rb * 64]);
            }
        }
        {
            const u16* sA = &sm[t & 1][0];
            const u16* sB = &sm[t & 1][64 * 64];
#pragma unroll
            for (int kk = 0; kk < 2; ++kk) {
                bf16x8 av[2], bv[2];
#pragma unroll
                for (int i = 0; i < 2; ++i) {
                    int row = wr * 32 + i * 16 + lr;
                    int e = (kk * 32 + lg * 8) ^ ((row & 7) << 3);
                    av[i] = *reinterpret_cast<const bf16x8*>(sA + row * 64 + e);
                }
#pragma unroll
                for (int j = 0; j < 2; ++j) {
                    int row = wc * 32 + j * 16 + lr;
                    int e = (kk * 32 + lg * 8) ^ ((row & 7) << 3);
                    bv[j] = *reinterpret_cast<const bf16x8*>(sB + row * 64 + e);
                }
#pragma unroll
                for (int i = 0; i < 2; ++i)
#pragma unroll
                    for (int j = 0; j < 2; ++j)
                        acc[i][j] = __builtin_amdgcn_mfma_f32_16x16x32_bf16(
                            av[i], bv[j], acc[i][j], 0, 0, 0);
            }
        }
        __syncthreads();
    }
#pragma unroll
    for (int i = 0; i < 2; ++i)
#pragma unroll
        for (int r = 0; r < 4; ++r) {
            int m = m0 + wr * 32 + i * 16 + lg * 4 + r;
            if (m >= M) continue;
#pragma unroll
            for (int j = 0; j < 2; ++j) {
                int n = n0 + wc * 32 + j * 16 + lr;
                if (n >= N) continue;
                float v = acc[i][j][r];
                size_t idx = (size_t)m * ldc + n;
                if (EPI == 1) {
                    atomicAdd((float*)Cv + idx, v);
                } else if (EPI == 2) {
                    ((float*)Cv)[idx] = v + e0[n] + e1[(size_t)(1 + (m % NPATCH)) * DM + n];
                } else {  // 4
                    ((u16*)Cv)[idx] = f2bf(v);
                }
            }
        }
}

// ---------------------------------------------------------------------------
// dt GEMM, single K-tile (K=64): dt^T = softplus(W_dt @ xdbl^T + dtb[m]).
// A = wd (bf16, [1536][64] zero-padded), B staged from f32 xdbl [1184][80].
// Grid (24, 19). Same LDS swizzle convention as gemm64.
// ---------------------------------------------------------------------------
__global__ __launch_bounds__(256) void gemm_dtf(
    const u16* __restrict__ A,      // layer slice of wd_all
    const float* __restrict__ Bx,   // xdbl [1184][80] f32
    const float* __restrict__ dtb,  // [1536] (layer slice)
    u16* __restrict__ dtT) {        // [1536][1184] bf16
    __shared__ u16 sA[64 * 64];
    __shared__ u16 sB[64 * 64];
    const int tid = threadIdx.x;
    const int m0 = blockIdx.x * 64, n0 = blockIdx.y * 64;
    const int lane = tid & 63, wid = tid >> 6;
    const int wr = wid >> 1, wc = wid & 1;
    const int lr = lane & 15, lg = lane >> 4;
    const int subrow = lane >> 3, kpart = lane & 7;
    const int kel = 8 * (kpart ^ subrow);
    // A: async 16B loads, pre-swizzled source
#pragma unroll
    for (int s = 0; s < 2; ++s) {
        int rb = wid * 16 + s * 8;
        gl_lds16(A + (size_t)(m0 + rb + subrow) * 64 + kel, &sA[rb * 64]);
    }
    // B: reg-stage f32 -> bf16 (cols 0..47 valid, 48..63 zero)
    {
        int r = tid >> 2, g0 = (tid & 3) * 2;
        int rn = min(n0 + r, MTOK - 1);
#pragma unroll
        for (int gi = 0; gi < 2; ++gi) {
            int g = g0 + gi;
            u16x8 w = { 0, 0, 0, 0, 0, 0, 0, 0 };
            if (g < 6) {
                float4 a = *reinterpret_cast<const float4*>(Bx + (size_t)rn * 80 + g * 8);
                float4 c = *reinterpret_cast<const float4*>(Bx + (size_t)rn * 80 + g * 8 + 4);
                w[0] = f2bf(a.x); w[1] = f2bf(a.y); w[2] = f2bf(a.z); w[3] = f2bf(a.w);
                w[4] = f2bf(c.x); w[5] = f2bf(c.y); w[6] = f2bf(c.z); w[7] = f2bf(c.w);
            }
            *reinterpret_cast<u16x8*>(&sB[r * 64 + ((g ^ (r & 7)) * 8)]) = w;
        }
    }
    __syncthreads();
    f32x4 acc[2][2] = {};
#pragma unroll
    for (int kk = 0; kk < 2; ++kk) {
        bf16x8 av[2], bv[2];
#pragma unroll
        for (int i = 0; i < 2; ++i) {
            int row = wr * 32 + i * 16 + lr;
            int e = (kk * 32 + lg * 8) ^ ((row & 7) << 3);
            av[i] = *reinterpret_cast<const bf16x8*>(sA + row * 64 + e);
        }
#pragma unroll
        for (int j = 0; j < 2; ++j) {
            int row = wc * 32 + j * 16 + lr;
            int e = (kk * 32 + lg * 8) ^ ((row & 7) << 3);
            bv[j] = *reinterpret_cast<const bf16x8*>(sB + row * 64 + e);
        }
#pragma unroll
        for (int i = 0; i < 2; ++i)
#pragma unroll
            for (int j = 0; j < 2; ++j)
                acc[i][j] = __builtin_amdgcn_mfma_f32_16x16x32_bf16(
                    av[i], bv[j], acc[i][j], 0, 0, 0);
    }
#pragma unroll
    for (int i = 0; i < 2; ++i)
#pragma unroll
        for (int r = 0; r < 4; ++r) {
            int m = m0 + wr * 32 + i * 16 + lg * 4 + r;
            float bias = dtb[m];
#pragma unroll
            for (int j = 0; j < 2; ++j) {
                int n = n0 + wc * 32 + j * 16 + lr;
                if (n >= MTOK) continue;
                float x = acc[i][j][r] + bias;
                dtT[(size_t)m * MT + n] = f2bf(x > 20.f ? x : log1pf(__expf(x)));
            }
        }
}

// ---------------------------------------------------------------------------
// Causal depthwise conv(4)+silu on channel-major xs^T.
// ---------------------------------------------------------------------------
template <int TC>
__device__ __forceinline__ void conv_piece(const u16* __restrict__ xrow,
                                           const float w0, const float w1,
                                           const float w2, const float w3,
                                           const float cbv,
                                           u16* __restrict__ sout) {
    constexpr int START = (TC == 0) ? 0 : (TC == 1) ? 32 : (TC == 2) ? 64 : 104;
    u16x8 buf[6];
#pragma unroll
    for (int i = 0; i < 6; ++i)
        buf[i] = *reinterpret_cast<const u16x8*>(xrow + START + 8 * i);
    const float wj[4] = { w0, w1, w2, w3 };
#pragma unroll
    for (int i = 0; i < 37; ++i) {
        const int t = TC * 37 + i;
        float acc = cbv;
#pragma unroll
        for (int j = 0; j < 4; ++j) {
            const int q = t - 3 + j;
            if (TC == 0 && q < 0) continue;      // folds at compile time
            const int idx = q - START;
            acc += bf2f(buf[idx >> 3][idx & 7]) * wj[j];
        }
        acc = acc * sigmoidf_(acc);
        sout[t] = f2bf(acc);
    }
}

__global__ __launch_bounds__(256) void k_conv(
    const u16* __restrict__ xzT,    // [3072][1184] (xs = rows 0..1535)
    const float* __restrict__ cw,   // [1536][4]
    const float* __restrict__ cb,   // [1536]
    u16* __restrict__ xcT,          // [1536][1184]
    u16* __restrict__ xcTok,        // [1184][1536]
    float* __restrict__ xdbl) {     // [1184][80] -> zeroed
    __shared__ u16 sxc[64][152];
    const int tid = threadIdx.x;
    const int d0 = blockIdx.x * 64, b = blockIdx.y;
    const int dl = tid & 63, tc = tid >> 6;
    const int d = d0 + dl;
    float4 w4 = *reinterpret_cast<const float4*>(&cw[d * 4]);
    float cbv = cb[d];
    const u16* xrow = xzT + (size_t)d * MT + b * SEQ;
    switch (tc) {
        case 0: conv_piece<0>(xrow, w4.x, w4.y, w4.z, w4.w, cbv, &sxc[dl][0]); break;
        case 1: conv_piece<1>(xrow, w4.x, w4.y, w4.z, w4.w, cbv, &sxc[dl][0]); break;
        case 2: conv_piece<2>(xrow, w4.x, w4.y, w4.z, w4.w, cbv, &sxc[dl][0]); break;
        default: conv_piece<3>(xrow, w4.x, w4.y, w4.z, w4.w, cbv, &sxc[dl][0]); break;
    }
    if (blockIdx.x == 0) {          // zero xdbl slice for this batch
        float4* xo = reinterpret_cast<float4*>(xdbl + (size_t)b * SEQ * 80);
        for (int c = tid; c < SEQ * 20; c += 256) xo[c] = make_float4(0.f, 0.f, 0.f, 0.f);
    }
    __syncthreads();
    for (int c = tid; c < 64 * 19; c += 256) {
        int dd = c / 19, ch = c % 19;
        size_t gbase = (size_t)(d0 + dd) * MT + b * SEQ;
        if (ch < 18)
            *reinterpret_cast<u16x8*>(&xcT[gbase + ch * 8]) =
                *reinterpret_cast<const u16x8*>(&sxc[dd][ch * 8]);
        else
            *reinterpret_cast<ushort4*>(&xcT[gbase + 144]) =
                *reinterpret_cast<const ushort4*>(&sxc[dd][144]);
    }
    if (tid < SEQ) {
        int t = tid;
        size_t gb = (size_t)(b * SEQ + t) * DI + d0;
#pragma unroll
        for (int g = 0; g < 8; ++g) {
            u16x8 v;
#pragma unroll
            for (int e = 0; e < 8; ++e) v[e] = sxc[g * 8 + e][t];
            *reinterpret_cast<u16x8*>(&xcTok[gb + g * 8]) = v;
        }
    }
}

// ---------------------------------------------------------------------------
// Selective scan: 16 lanes per (b,d); 8-step chunks, vectorized loads.
// B/C staged from f32 xdbl into LDS (conflict-free 149-pad).
// ---------------------------------------------------------------------------
__global__ __launch_bounds__(256) void k_scan(
    const u16* __restrict__ dtT,    // [1536][1184] bf16
    const u16* __restrict__ xcT,    // [1536][1184] bf16
    const u16* __restrict__ xzT,    // [3072][1184] bf16 (z = rows 1536..)
    const float* __restrict__ xdbl, // [1184][80] f32 (cols 48..63=B, 64..79=C)
    const float* __restrict__ A_log,// [1536][16] (layer slice)
    const float* __restrict__ Dp,   // [1536]
    u16* __restrict__ y) {          // [1184][1536] bf16 token-major
    __shared__ float sBC[32][149];
    __shared__ u16 sy[16][152];
    const int tid = threadIdx.x;
    const int d0 = blockIdx.x * 16, b = blockIdx.y;
    const int dl = tid >> 4, n = tid & 15;
    const int d = d0 + dl;
    for (int i = tid; i < 32 * SEQ; i += 256) {
        int t = i >> 5, c = i & 31;
        sBC[c][t] = xdbl[(size_t)(b * SEQ + t) * 80 + 48 + c];
    }
    const float An = -__expf(A_log[d * DST + n]);
    const float Dv = Dp[d];
    const u16* dtrow = dtT + (size_t)d * MT + b * SEQ;
    const u16* xcrow = xcT + (size_t)d * MT + b * SEQ;
    const u16* zrow  = xzT + (size_t)(DI + d) * MT + b * SEQ;
    float h = 0.f;
    __syncthreads();
    for (int t0 = 0; t0 < SEQ; t0 += 8) {
        u16x8 dt8 = *reinterpret_cast<const u16x8*>(dtrow + t0);
        u16x8 xc8 = *reinterpret_cast<const u16x8*>(xcrow + t0);
        u16x8 z8  = *reinterpret_cast<const u16x8*>(zrow + t0);
#pragma unroll
        for (int j = 0; j < 8; ++j) {
            if (t0 + j < SEQ) {
                float dtv = bf2f(dt8[j]);
                float xcv = bf2f(xc8[j]);
                float e = __expf(dtv * An);
                h = e * h + (dtv * xcv) * sBC[n][t0 + j];
                float yp = h * sBC[16 + n][t0 + j];
                yp += __shfl_xor(yp, 1, 64);
                yp += __shfl_xor(yp, 2, 64);
                yp += __shfl_xor(yp, 4, 64);
                yp += __shfl_xor(yp, 8, 64);
                if (n == 0) {
                    float zv = bf2f(z8[j]);
                    sy[dl][t0 + j] = f2bf((yp + xcv * Dv) * (zv * sigmoidf_(zv)));
                }
            }
        }
    }
    __syncthreads();
    if (tid < SEQ) {
        int t = tid;
        size_t gb = (size_t)(b * SEQ + t) * DI + d0;
#pragma unroll
        for (int g = 0; g < 2; ++g) {
            u16x8 v;
#pragma unroll
            for (int e = 0; e < 8; ++e) v[e] = sy[g * 8 + e][t];
            *reinterpret_cast<u16x8*>(&y[gb + g * 8]) = v;
        }
    }
}

// ---------------------------------------------------------------------------
// Bulk weight convert, 8 f32 per thread, region by cascading int compares.
// Regions (pair counts, 1 pair = 8 elems):
//   conv_w 73728 | W_in 3538944 | W_out 1769472 | W_x 184320 | W_dt 147456
// W_dt: dest [12*1536][64] (src stride 48, cols 48..63 zero) -> shifts only.
// ---------------------------------------------------------------------------
#define PCW 73728
#define PWI 3538944
#define PWO 1769472
#define PWX 184320
#define PWD 147456
__global__ __launch_bounds__(256) void k_cvtw_all(
    const float* __restrict__ cwsrc, const float* __restrict__ Wi,
    const float* __restrict__ Wo, const float* __restrict__ Wx,
    const float* __restrict__ Wd,
    u16* __restrict__ ocw, u16* __restrict__ oi, u16* __restrict__ oo,
    u16* __restrict__ ox, u16* __restrict__ od) {
    int p = blockIdx.x * 256 + threadIdx.x;
    const float* src;
    u16* dst;
    bool zero_hi = false;
    if (p < PCW) {
        src = cwsrc + (size_t)p * 8; dst = ocw + (size_t)p * 8;
    } else if (p < PCW + PWI) {
        size_t e = (size_t)(p - PCW) * 8; src = Wi + e; dst = oi + e;
    } else if (p < PCW + PWI + PWO) {
        size_t e = (size_t)(p - PCW - PWI) * 8; src = Wo + e; dst = oo + e;
    } else if (p < PCW + PWI + PWO + PWX) {
        size_t e = (size_t)(p - PCW - PWI - PWO) * 8; src = Wx + e; dst = ox + e;
    } else {
        int q = p - PCW - PWI - PWO - PWX;           // < PWD
        int ei = q * 8;                               // dest elem
        int rw = ei >> 6, c0 = ei & 63;               // rw = l*1536+row
        dst = od + ei;
        if (c0 < DTR) { src = Wd + (size_t)rw * DTR + c0; }
        else { src = Wd; zero_hi = true; }            // dummy, will zero
    }
    u16x8 w;
    if (zero_hi) {
        w = (u16x8){ 0, 0, 0, 0, 0, 0, 0, 0 };
    } else {
        float4 a = *reinterpret_cast<const float4*>(src);
        float4 c = *reinterpret_cast<const float4*>(src + 4);
        w[0] = f2bf(a.x); w[1] = f2bf(a.y); w[2] = f2bf(a.z); w[3] = f2bf(a.w);
        w[4] = f2bf(c.x); w[5] = f2bf(c.y); w[6] = f2bf(c.z); w[7] = f2bf(c.w);
    }
    *reinterpret_cast<u16x8*>(dst) = w;
}

// ---------------------------------------------------------------------------
extern "C" void kernel_launch(void* const* d_in, const int* in_sizes, int n_in,
                              void* d_out, int out_size, void* d_ws, size_t ws_size,
                              hipStream_t stream) {
    const float* pixel  = (const float*)d_in[0];
    const float* noise  = (const float*)d_in[1];
    const float* conv_w = (const float*)d_in[2];
    const float* conv_b = (const float*)d_in[3];
    const float* cls    = (const float*)d_in[4];
    const float* pos    = (const float*)d_in[5];
    const float* ln_w   = (const float*)d_in[6];
    const float* ln_b   = (const float*)d_in[7];
    const float* W_in   = (const float*)d_in[8];
    const float* c1w    = (const float*)d_in[9];
    const float* c1b    = (const float*)d_in[10];
    const float* W_x    = (const float*)d_in[11];
    const float* W_dt   = (const float*)d_in[12];
    const float* dtb    = (const float*)d_in[13];
    const float* A_log  = (const float*)d_in[14];
    const float* Dp     = (const float*)d_in[15];
    const float* W_out  = (const float*)d_in[16];
    const float* lnf_w  = (const float*)d_in[17];
    const float* lnf_b  = (const float*)d_in[18];

    float* out = (float*)d_out;
    float* h = out;                                   // [1184][768] f32
    float* out_mask    = out + MTOK * DM;
    float* out_restore = out + MTOK * DM + BATCH * NPATCH;

    // ---- workspace layout (byte offsets, 64-aligned, tail-padded) ----
    char* wsb = (char*)d_ws;
    u16*  xzT     = (u16*)(wsb + 0);          // 7,274,496 (+64 pad)
    u16*  xcT     = (u16*)(wsb + 7274560);    // 3,637,248 (+64)
    u16*  xcTok   = (u16*)(wsb + 10911872);   // 3,637,248
    u16*  dtT     = (u16*)(wsb + 14549120);   // 3,637,248 (+64)
    u16*  yb      = (u16*)(wsb + 18186432);   // 3,637,248
    u16*  xln_bf  = (u16*)(wsb + 21823680);   // 1,818,624
    float* xdbl   = (float*)(wsb + 23642304); // 378,880
    u16*  apatch  = (u16*)(wsb + 24021184);   // 2,408,448
    float* embed  = (float*)(wsb + 26429632); // 4,816,896
    int*  ids     = (int*)(wsb + 31246528);   // 6,272
    u16*  cw_bf   = (u16*)(wsb + 31252864);   // 1,179,648
    u16*  wi_all  = (u16*)(wsb + 32432512);   // 56,623,104
    u16*  wo_all  = wi_all + 28311552;        // 28,311,552 B
    u16*  wx_all  = wo_all + 14155776;        // 2,949,120 B
    u16*  wd_all  = wx_all + 1474560;         // 2,359,296 B -> end ~123 MB

    // ---- setup ----
    k_im2col<<<1176, 256, 0, stream>>>(pixel, apatch);
    k_mask<<<BATCH, 256, 0, stream>>>(noise, ids, out_mask, out_restore);
    k_cvtw_all<<<22320, 256, 0, stream>>>(conv_w, W_in, W_out, W_x, W_dt,
                                          cw_bf, wi_all, wo_all, wx_all, wd_all);
    gemm64<2><<<dim3(25, 12, 1), 256, 0, stream>>>(
        apatch, 768, 1568, cw_bf, 768, 768, embed, DM, 768, conv_b, pos);
    k_build_h<<<MTOK, 256, 0, stream>>>(embed, ids, cls, pos, h);

    // ---- layers ----
    for (int l = 0; l < 12; ++l) {
        const u16* wi = wi_all + (size_t)l * 2359296;
        const u16* wo = wo_all + (size_t)l * 1179648;
        const u16* wx = wx_all + (size_t)l * 122880;
        const u16* wd = wd_all + (size_t)l * 98304;
        k_layernorm<1><<<MTOK, 256, 0, stream>>>(h, ln_w + l * DM, ln_b + l * DM, xln_bf);
        // xz^T = W_in @ xln^T : A=W_in rows (3072), B=xln rows (1184)
        gemm64<4><<<dim3(48, 19, 1), 256, 0, stream>>>(
            wi, DM, 3072, xln_bf, DM, MTOK, xzT, MT, DM, nullptr, nullptr);
        // conv+silu -> xc^T and token-major xc; zero xdbl
        k_conv<<<dim3(24, 8), 256, 0, stream>>>(
            xzT, c1w + l * DI * 4, c1b + l * DI, xcT, xcTok, xdbl);
        // xdbl += xc @ W_x^T (split-K 8 x 192)
        gemm64<1><<<dim3(19, 2, 8), 256, 0, stream>>>(
            xcTok, DI, MTOK, wx, DI, 80, xdbl, 80, 192, nullptr, nullptr);
        // dt^T = softplus(W_dt @ xdbl^T + dtb[m])  (B from f32, K=64)
        gemm_dtf<<<dim3(24, 19), 256, 0, stream>>>(wd, xdbl, dtb + l * DI, dtT);
        k_scan<<<dim3(96, 8), 256, 0, stream>>>(
            dtT, xcT, xzT, xdbl, A_log + (size_t)l * DI * DST, Dp + l * DI, yb);
        // h += y @ W_out^T (split-K 2 x 768, atomicAdd into residual)
        gemm64<1><<<dim3(19, 12, 2), 256, 0, stream>>>(
            yb, DI, MTOK, wo, DI, DM, h, DM, 768, nullptr, nullptr);
    }
    k_layernorm<0><<<MTOK, 256, 0, stream>>>(h, lnf_w, lnf_b, h);
}